// Round 15
// baseline (937.923 us; speedup 1.0000x reference)
//
#include <hip/hip_runtime.h>

typedef __bf16 bf16x8 __attribute__((ext_vector_type(8)));
typedef float f32x4 __attribute__((ext_vector_type(4)));
typedef unsigned int uint32x4 __attribute__((ext_vector_type(4)));

#define DD 256
#define VV 1024
#define BN 16
#define KC1 36    // extended-K chunks of 8 (288/8): 32 data + c2 + zeros
#define WVA 8     // waves in kernel A
#define VCH 128   // V-chunk per wave in kernel A
#define TILES 8   // tiles per persistent block (4096 tiles / 512 blocks)

__device__ __forceinline__ unsigned short f2bf(float f) {
    unsigned int b = __float_as_uint(f);
    b += 0x7FFFu + ((b >> 16) & 1u);
    return (unsigned short)(b >> 16);
}

// async global->LDS, 16B per lane. LDS dst must be WAVE-UNIFORM base
// (HW adds lane*16); global src is per-lane.
typedef __attribute__((address_space(3))) unsigned int lds_uint;
typedef __attribute__((address_space(1))) const unsigned int glb_uint;
__device__ __forceinline__ void dma16(const void* g, void* l) {
    __builtin_amdgcn_global_load_lds((glb_uint*)g, (lds_uint*)l, 16, 0, 0);
}

// Prep: fragment-major, sigma-permuted codebook layouts.
// sigma: element d -> kc = (d>>5)*4 + ((d>>2)&3), j = (d&3) + ((d>>4)&1)*4.
__global__ __launch_bounds__(256) void vq_prep_kernel(
    const float* __restrict__ cb,
    unsigned short* __restrict__ cbA,   // [V/16][KC1][16][8]
    unsigned short* __restrict__ cbB)   // [D/16][128][16][8]
{
    int v = blockIdx.x;
    int t = threadIdx.x;
    float val = cb[(size_t)v * DD + t];
    unsigned short h = f2bf(val);
    const int vtile = v >> 4, vi = v & 15;
    const int kc_t = (t >> 5) * 4 + ((t >> 2) & 3);
    const int j_t  = (t & 3) + ((t >> 4) & 1) * 4;
    cbA[(((size_t)vtile * KC1 + kc_t) * 16 + vi) * 8 + j_t] = h;
    const int kcv = (v >> 5) * 4 + ((v >> 2) & 3);
    const int jv  = (v & 3) + ((v >> 4) & 1) * 4;
    cbB[(((size_t)(t >> 4) * 128 + kcv) * 16 + (t & 15)) * 8 + jv] = h;

    float p = val * val;
#pragma unroll
    for (int d = 1; d < 64; d <<= 1) p += __shfl_xor(p, d);
    __shared__ float ps[4];
    if ((t & 63) == 0) ps[t >> 6] = p;
    __syncthreads();
    if (t < 32) {
        float c2 = ps[0] + ps[1] + ps[2] + ps[3];
        float m = -0.5f * c2;
        unsigned short hi = f2bf(m);
        float hif = __uint_as_float((unsigned int)hi << 16);
        unsigned short lo = f2bf(m - hif);
        unsigned short o = (t == 0) ? hi : ((t == 1) ? lo : (unsigned short)0);
        cbA[(((size_t)vtile * KC1 + 32 + (t >> 3)) * 16 + vi) * 8 + (t & 7)] = o;
    }
}

// Prep-x: x[N][256] f32 -> xbf[N][256] bf16 in sigma-slot order with
// per-row granule XOR swizzle (gi ^= row&7), + x2[N] = ||x_row||^2.
// Slot map (matches afr fragments): d = kt*32 + lrow*4 + (j<4 ? j : 16+j-4)
//  -> slot kt*32 + lrow*8 + j, granule gi = kt*4+lrow.
// 16 threads per row; thread c handles d = c*16 .. c*16+15 (kt=c>>1).
__global__ __launch_bounds__(256) void vq_prepx_kernel(
    const float* __restrict__ x,
    unsigned short* __restrict__ xbf,   // [N][256] bf16 (swizzled slots)
    float* __restrict__ x2g)            // [N]
{
    const int t = threadIdx.x;
    const int r = blockIdx.x * 16 + (t >> 4);
    const int c = t & 15;
    const float* xr = x + (size_t)r * DD + c * 16;
    float4 v4[4];
#pragma unroll
    for (int i = 0; i < 4; ++i) v4[i] = *reinterpret_cast<const float4*>(xr + i * 4);
    float vals[16] = {v4[0].x, v4[0].y, v4[0].z, v4[0].w,
                      v4[1].x, v4[1].y, v4[1].z, v4[1].w,
                      v4[2].x, v4[2].y, v4[2].z, v4[2].w,
                      v4[3].x, v4[3].y, v4[3].z, v4[3].w};
    float s = 0.f;
#pragma unroll
    for (int i = 0; i < 16; ++i) s += vals[i] * vals[i];
#pragma unroll
    for (int d = 1; d < 16; d <<= 1) s += __shfl_xor(s, d);
    if (c == 0) x2g[r] = s;

    const int kt = c >> 1;
    unsigned short* orow = xbf + (size_t)r * DD;
#pragma unroll
    for (int g = 0; g < 4; ++g) {   // g = lrow
        ushort4 h;
        h.x = f2bf(vals[g * 4 + 0]);
        h.y = f2bf(vals[g * 4 + 1]);
        h.z = f2bf(vals[g * 4 + 2]);
        h.w = f2bf(vals[g * 4 + 3]);
        const int pos = (((kt * 4 + g) ^ (r & 7)) << 3) + ((c & 1) << 2);
        *reinterpret_cast<ushort4*>(orow + pos) = h;
    }
}

// Kernel A (persistent): GEMM1 + fused no-max gumbel-softmax -> out_p.
// 512 blocks x 8 tiles. x (bf16, pre-converted) and gumbel staged to LDS via
// global_load_lds; DMA(it+1) issued after B1 -> overlaps GEMM1+softmax of
// tile it. pe overwrites u4 in place (reg budget ~100 < 128: no spill).
__global__ __launch_bounds__(512, 4) void vq_softmax_kernel(
    const float* __restrict__ gum,      // [N][V]
    const unsigned short* __restrict__ xbf,   // [N][256] bf16 swizzled
    const float* __restrict__ x2g,      // [N]
    const unsigned short* __restrict__ cbA,
    float* __restrict__ out_p)          // [N][V]
{
    __shared__ __align__(16) unsigned short xb16[BN * DD];  // 8 KB
    __shared__ __align__(16) float gbuf[BN * VV];           // 64 KB
    __shared__ float sred[WVA * BN];                        // 512 B

    const int tid  = threadIdx.x;
    const int wave = tid >> 6;    // 0..7
    const int lane = tid & 63;
    const int lrow = (lane >> 4) & 3;
    const int lcol = lane & 15;
    const int vb   = wave * VCH;
    const int laneoff = lrow * 128 + lcol * 8;
    const int tile0 = blockIdx.x * TILES;

    // ---- prologue: DMA x-bf16 + gumbel for tile 0 ----
    {
        const int row0 = tile0 * BN;
        // x: 8 KB = 8 x 1KB; wave w copies rows 2w,2w+1
        dma16(xbf + (size_t)(row0 + wave * 2) * DD + lane * 8,
              &xb16[wave * 2 * DD]);
#pragma unroll
        for (int h = 0; h < 2; ++h) {
            const int r = wave * 2 + h;
            const float* gsrc = gum + (size_t)(row0 + r) * VV;
#pragma unroll
            for (int i = 0; i < 4; ++i) {
                const int g = i * 64 + lane;
                dma16(gsrc + ((g ^ (r & 7)) << 2), &gbuf[r * VV + i * 256]);
            }
        }
    }

#pragma unroll 1
    for (int it = 0; it < TILES; ++it) {
        const int row0 = (tile0 + it) * BN;
        const float x2 = x2g[row0 + lcol];   // L2-hit scalar

        // B0: DMA(it) landed for all waves (full fence + vmcnt drain).
        __syncthreads();

        // ---- gumbel tile -> u4 regs (consume gbuf early) ----
        f32x4 u4[8];
#pragma unroll
        for (int nt = 0; nt < 8; ++nt) {
            const int gg = ((vb >> 2) + nt * 4 + lrow) ^ (lcol & 7);
            u4[nt] = *reinterpret_cast<const f32x4*>(&gbuf[lcol * VV + gg * 4]);
        }

        // ---- afr direct from bf16 LDS (no conversion) ----
        bf16x8 afr[9];
#pragma unroll
        for (int kt = 0; kt < 8; ++kt) {
            const int gi = (kt * 4 + lrow) ^ (lcol & 7);
            afr[kt] = __builtin_bit_cast(bf16x8,
                *reinterpret_cast<const uint32x4*>(&xb16[lcol * DD + gi * 8]));
        }
        {
            uint32x4 w = {0u, 0u, 0u, 0u};
            if (lrow == 0) w[0] = 0x3F803F80u;  // bf16 1.0 pair at c2 slots
            afr[8] = __builtin_bit_cast(bf16x8, w);
        }

        // B1: xb16 + gbuf fully consumed into registers by all waves.
        __syncthreads();

        // ---- issue DMA for tile it+1 (overlaps GEMM1 + softmax below) ----
        if (it + 1 < TILES) {
            const int nrow0 = (tile0 + it + 1) * BN;
            dma16(xbf + (size_t)(nrow0 + wave * 2) * DD + lane * 8,
                  &xb16[wave * 2 * DD]);
#pragma unroll
            for (int h = 0; h < 2; ++h) {
                const int r = wave * 2 + h;
                const float* gsrc = gum + (size_t)(nrow0 + r) * VV;
#pragma unroll
                for (int i = 0; i < 4; ++i) {
                    const int g = i * 64 + lane;
                    dma16(gsrc + ((g ^ (r & 7)) << 2), &gbuf[r * VV + i * 256]);
                }
            }
        }

        // ---- GEMM1 (swapped): acc[nt]: v = vb+16nt+4lrow+r, x-row = lcol ----
        f32x4 acc[8];
#pragma unroll
        for (int nt = 0; nt < 8; ++nt) acc[nt] = (f32x4){0.f, 0.f, 0.f, 0.f};
#pragma unroll
        for (int nt = 0; nt < 8; ++nt) {
            const unsigned short* ap =
                cbA + ((size_t)(vb >> 4) + nt) * (KC1 * 128) + laneoff;
#pragma unroll
            for (int kt = 0; kt < 9; ++kt) {
                bf16x8 cfr = __builtin_bit_cast(bf16x8,
                    *reinterpret_cast<const uint32x4*>(ap + kt * 512));
                acc[nt] = __builtin_amdgcn_mfma_f32_16x16x32_bf16(cfr, afr[kt], acc[nt], 0, 0, 0);
            }
        }

        // ---- single-pass no-max softmax; pe overwrites u4 in place ----
        float ss = 0.f;
#pragma unroll
        for (int nt = 0; nt < 8; ++nt) {
#pragma unroll
            for (int r = 0; r < 4; ++r) {
                float u = fminf(fmaxf(u4[nt][r], 1e-10f), 1.0f - 1e-10f);
                float l2u = __builtin_amdgcn_logf(u);           // log2(u)
                float t = u - 1.0f;
                float pp = t * (1.0f + t * (-0.5f + t * (0.33333333f + t * (-0.25f + t * 0.2f))));
                float w = (u >= 0.984375f) ? -pp : (l2u * -0.69314718f);
                float l2w = __builtin_amdgcn_logf(w);           // log2(w)
                float d2 = fmaxf(__builtin_fmaf(-2.0f, acc[nt][r], x2), 1e-12f);
                float dist = __builtin_amdgcn_sqrtf(d2);
                float lg2 = __builtin_fmaf(-0.72134752f, dist, -0.5f * l2w);
                float e = __builtin_amdgcn_exp2f(lg2);
                u4[nt][r] = e;
                ss += e;
            }
        }
        ss += __shfl_xor(ss, 16);
        ss += __shfl_xor(ss, 32);   // row sum for row lcol (this V-chunk)

        if (lane < 16) sred[wave * 16 + lane] = ss;
        // B2: sred visible; DMA(it+1) drained (its window was GEMM1+softmax).
        __syncthreads();

        // ---- Z, rinv, out_p stores ----
        float Z = 0.f;
#pragma unroll
        for (int w = 0; w < WVA; ++w) Z += sred[w * 16 + lcol];
        const float rinv = 1.0f / Z;

        float* oprow = out_p + (size_t)(row0 + lcol) * VV + vb + lrow * 4;
#pragma unroll
        for (int nt = 0; nt < 8; ++nt)
            *reinterpret_cast<float4*>(oprow + nt * 16) =
                (float4){u4[nt][0] * rinv, u4[nt][1] * rinv,
                         u4[nt][2] * rinv, u4[nt][3] * rinv};
    }
}

// Kernel B: out_q = prob @ cb. 64 rows/block (4 row-groups of 16), 4 waves
// owning D-chunks of 64; cbB fragments reused across the 4 row-groups.
__global__ __launch_bounds__(256, 4) void vq_gemm2_kernel(
    const float* __restrict__ out_p,      // [N][V]
    const unsigned short* __restrict__ cbB,
    float* __restrict__ out_q)            // [N][D]
{
    const int tid  = threadIdx.x;
    const int wave = tid >> 6;
    const int lane = tid & 63;
    const int lrow = (lane >> 4) & 3;
    const int lcol = lane & 15;
    const int row0 = blockIdx.x * 64;
    const int dbw  = wave * 64;
    const int laneoff = lrow * 128 + lcol * 8;

    const unsigned short* bb =
        cbB + (size_t)(dbw >> 4) * (128 * 128) + laneoff;

    f32x4 q[4][4];
#pragma unroll
    for (int g = 0; g < 4; ++g)
#pragma unroll
        for (int nt = 0; nt < 4; ++nt) q[g][nt] = (f32x4){0.f, 0.f, 0.f, 0.f};

#pragma unroll 2
    for (int kt = 0; kt < 32; ++kt) {
        bf16x8 bfr[4];
#pragma unroll
        for (int nt = 0; nt < 4; ++nt)
            bfr[nt] = __builtin_bit_cast(bf16x8,
                *reinterpret_cast<const uint32x4*>(bb + nt * 16384 + kt * 512));
#pragma unroll
        for (int g = 0; g < 4; ++g) {
            const float* pr =
                out_p + (size_t)(row0 + g * 16 + lcol) * VV + kt * 32 + lrow * 4;
            f32x4 a = *reinterpret_cast<const f32x4*>(pr);
            f32x4 b = *reinterpret_cast<const f32x4*>(pr + 16);
            bf16x8 pfr;
#pragma unroll
            for (int j = 0; j < 4; ++j) {
                pfr[j]     = (__bf16)a[j];
                pfr[j + 4] = (__bf16)b[j];
            }
#pragma unroll
            for (int nt = 0; nt < 4; ++nt)
                q[g][nt] = __builtin_amdgcn_mfma_f32_16x16x32_bf16(pfr, bfr[nt], q[g][nt], 0, 0, 0);
        }
    }

#pragma unroll
    for (int g = 0; g < 4; ++g) {
        float* qrow0 = out_q + (size_t)(row0 + g * 16 + lrow * 4) * DD + dbw + lcol;
#pragma unroll
        for (int r = 0; r < 4; ++r) {
            float* qr = qrow0 + r * DD;
#pragma unroll
            for (int nt = 0; nt < 4; ++nt) qr[nt * 16] = q[g][nt][r];
        }
    }
}

extern "C" void kernel_launch(void* const* d_in, const int* in_sizes, int n_in,
                              void* d_out, int out_size, void* d_ws, size_t ws_size,
                              hipStream_t stream) {
    (void)in_sizes; (void)n_in; (void)out_size; (void)ws_size;
    const float* x   = (const float*)d_in[0];   // [16,4096,256]
    const float* cb  = (const float*)d_in[1];   // [1024,256]
    const float* gum = (const float*)d_in[2];   // [65536,1024]

    const int N = 16 * 4096;
    float* out_q = (float*)d_out;                       // [N][256], 64 MB
    float* out_p = out_q + (size_t)N * DD;              // [N][1024]

    // scratch inside the out_q region (B overwrites it after A consumes):
    unsigned short* xbf = (unsigned short*)out_q;       // 32 MB bf16 x
    float* x2g = out_q + (size_t)8 * 1024 * 1024;       // 256 KB at +32 MB

    unsigned short* cbA = (unsigned short*)d_ws;        // 576 KB fragment-major
    unsigned short* cbB = cbA + (size_t)64 * KC1 * 128; // 512 KB fragment-major

    vq_prep_kernel<<<VV, 256, 0, stream>>>(cb, cbA, cbB);
    vq_prepx_kernel<<<N / 16, 256, 0, stream>>>(x, xbf, x2g);
    vq_softmax_kernel<<<(N / BN) / TILES, 512, 0, stream>>>(gum, xbf, x2g, cbA, out_p);
    vq_gemm2_kernel<<<N / 64, 256, 0, stream>>>(out_p, cbB, out_q);
}

// Round 16
// 337.150 us; speedup vs baseline: 2.7819x; 2.7819x over previous
//
#include <hip/hip_runtime.h>

typedef __bf16 bf16x8 __attribute__((ext_vector_type(8)));
typedef float f32x4 __attribute__((ext_vector_type(4)));
typedef unsigned int uint32x4 __attribute__((ext_vector_type(4)));

#define DD 256
#define VV 1024
#define BN 16
#define KC1 36   // extended-K chunks of 8 (288/8): 32 data + c2 + zeros
#define WVA 8    // waves per block
#define VCH 128  // V-chunk per wave

__device__ __forceinline__ unsigned short f2bf(float f) {
    unsigned int b = __float_as_uint(f);
    b += 0x7FFFu + ((b >> 16) & 1u);
    return (unsigned short)(b >> 16);
}

// async global->LDS, 16B per lane. LDS dst must be WAVE-UNIFORM base
// (HW adds lane*16); global src is per-lane.
typedef __attribute__((address_space(3))) unsigned int lds_uint;
typedef __attribute__((address_space(1))) const unsigned int glb_uint;
__device__ __forceinline__ void dma16(const float* g, float* l) {
    __builtin_amdgcn_global_load_lds((glb_uint*)g, (lds_uint*)l, 16, 0, 0);
}

// Prep: fragment-major, sigma-permuted codebook layouts (verified R8+).
// sigma: element d -> kc = (d>>5)*4 + ((d>>2)&3), j = (d&3) + ((d>>4)&1)*4.
__global__ __launch_bounds__(256) void vq_prep_kernel(
    const float* __restrict__ cb,
    unsigned short* __restrict__ cbA,   // [V/16][KC1][16][8]
    unsigned short* __restrict__ cbB)   // [D/16][128][16][8]
{
    int v = blockIdx.x;
    int t = threadIdx.x;
    float val = cb[(size_t)v * DD + t];
    unsigned short h = f2bf(val);
    const int vtile = v >> 4, vi = v & 15;
    const int kc_t = (t >> 5) * 4 + ((t >> 2) & 3);
    const int j_t  = (t & 3) + ((t >> 4) & 1) * 4;
    cbA[(((size_t)vtile * KC1 + kc_t) * 16 + vi) * 8 + j_t] = h;
    const int kcv = (v >> 5) * 4 + ((v >> 2) & 3);
    const int jv  = (v & 3) + ((v >> 4) & 1) * 4;
    cbB[(((size_t)(t >> 4) * 128 + kcv) * 16 + (t & 15)) * 8 + jv] = h;

    float p = val * val;
#pragma unroll
    for (int d = 1; d < 64; d <<= 1) p += __shfl_xor(p, d);
    __shared__ float ps[4];
    if ((t & 63) == 0) ps[t >> 6] = p;
    __syncthreads();
    if (t < 32) {
        float c2 = ps[0] + ps[1] + ps[2] + ps[3];
        float m = -0.5f * c2;
        unsigned short hi = f2bf(m);
        float hif = __uint_as_float((unsigned int)hi << 16);
        unsigned short lo = f2bf(m - hif);
        unsigned short o = (t == 0) ? hi : ((t == 1) ? lo : (unsigned short)0);
        cbA[(((size_t)vtile * KC1 + 32 + (t >> 3)) * 16 + vi) * 8 + (t & 7)] = o;
    }
}

// Fused main kernel (launch-per-tile, R10-verified internals + fused GEMM2):
// GEMM1 + no-max gumbel-softmax + prob->LDS(bf16, sigma-slot order) + GEMM2.
// LDS exactly 80 KB (xbuf reused for sred; gbuf reused for prob) -> 2 blk/CU.
__global__ __launch_bounds__(512, 4) void vq_main_kernel(
    const float* __restrict__ x,          // [N][D]
    const float* __restrict__ gum,        // [N][V]
    const unsigned short* __restrict__ cbA,
    const unsigned short* __restrict__ cbB,
    float* __restrict__ out_q,            // [N][D]
    float* __restrict__ out_p)            // [N][V]
{
    __shared__ __align__(16) float xbuf[BN * DD];   // 16 KB (later: sred)
    __shared__ __align__(16) float gbuf[BN * VV];   // 64 KB (later: prob bf16)

    const int tid  = threadIdx.x;
    const int wave = tid >> 6;    // 0..7
    const int lane = tid & 63;
    const int lrow = (lane >> 4) & 3;
    const int lcol = lane & 15;
    const int row0 = blockIdx.x * BN;
    const int vb   = wave * VCH;
    const int laneoff = lrow * 128 + lcol * 8;

    // ---- DMA issue: x rows (2/wave) then gumbel rows (2/wave x 4 KB) ----
    // 16B-granule XOR swizzle (both-sides involution) on the global source.
#pragma unroll
    for (int h = 0; h < 2; ++h) {
        const int r = wave * 2 + h;
        dma16(x + (size_t)(row0 + r) * DD + (((lane ^ (r & 7)) & 63) << 2),
              &xbuf[r * DD]);
    }
#pragma unroll
    for (int h = 0; h < 2; ++h) {
        const int r = wave * 2 + h;
        const float* gsrc = gum + (size_t)(row0 + r) * VV;
#pragma unroll
        for (int i = 0; i < 4; ++i) {
            const int g = i * 64 + lane;
            dma16(gsrc + ((g ^ (r & 7)) << 2), &gbuf[r * VV + i * 256]);
        }
    }
    // wait x (2 oldest of 10 per wave), leave 8 gumbel DMAs in flight
    asm volatile("s_waitcnt vmcnt(8)" ::: "memory");
    __builtin_amdgcn_sched_barrier(0);
    __builtin_amdgcn_s_barrier();

    // ---- afr from xbuf (sigma slots) + x2; native bf16 casts ----
    bf16x8 afr[9];
    float x2 = 0.f;
#pragma unroll
    for (int kt = 0; kt < 8; ++kt) {
        const int g1 = (kt * 8 + lrow) ^ (lcol & 7);
        const int g2 = (kt * 8 + lrow + 4) ^ (lcol & 7);
        f32x4 a = *reinterpret_cast<const f32x4*>(&xbuf[lcol * DD + g1 * 4]);
        f32x4 b = *reinterpret_cast<const f32x4*>(&xbuf[lcol * DD + g2 * 4]);
        bf16x8 fr;
#pragma unroll
        for (int j = 0; j < 4; ++j) {
            x2 += a[j] * a[j] + b[j] * b[j];
            fr[j]     = (__bf16)a[j];
            fr[j + 4] = (__bf16)b[j];
        }
        afr[kt] = fr;
    }
    x2 += __shfl_xor(x2, 16);
    x2 += __shfl_xor(x2, 32);   // full-row x2 of row lcol
    {
        uint32x4 w = {0u, 0u, 0u, 0u};
        if (lrow == 0) w[0] = 0x3F803F80u;  // bf16 1.0 pair at c2 slots
        afr[8] = __builtin_bit_cast(bf16x8, w);
    }

    // ---- GEMM1 (swapped): acc[nt]: v = vb+16nt+4lrow+r, x-row = lcol ----
    f32x4 acc[8];
#pragma unroll
    for (int nt = 0; nt < 8; ++nt) acc[nt] = (f32x4){0.f, 0.f, 0.f, 0.f};
#pragma unroll
    for (int nt = 0; nt < 8; ++nt) {
        const unsigned short* ap =
            cbA + ((size_t)(vb >> 4) + nt) * (KC1 * 128) + laneoff;
#pragma unroll
        for (int kt = 0; kt < 9; ++kt) {
            bf16x8 cfr = __builtin_bit_cast(bf16x8,
                *reinterpret_cast<const uint32x4*>(ap + kt * 512));
            acc[nt] = __builtin_amdgcn_mfma_f32_16x16x32_bf16(cfr, afr[kt], acc[nt], 0, 0, 0);
        }
    }

    // gumbel DMA done + all waves past xbuf reads
    asm volatile("s_waitcnt vmcnt(0)" ::: "memory");
    __builtin_amdgcn_sched_barrier(0);
    __builtin_amdgcn_s_barrier();

    // ---- gumbel from LDS + single-pass no-max softmax (pe overwrites u4) ----
    f32x4 u4[8];
#pragma unroll
    for (int nt = 0; nt < 8; ++nt) {
        const int gg = ((vb >> 2) + nt * 4 + lrow) ^ (lcol & 7);
        u4[nt] = *reinterpret_cast<const f32x4*>(&gbuf[lcol * VV + gg * 4]);
    }

    float ss = 0.f;
#pragma unroll
    for (int nt = 0; nt < 8; ++nt) {
#pragma unroll
        for (int r = 0; r < 4; ++r) {
            float u = fminf(fmaxf(u4[nt][r], 1e-10f), 1.0f - 1e-10f);
            float l2u = __builtin_amdgcn_logf(u);           // log2(u)
            float t = u - 1.0f;
            float pp = t * (1.0f + t * (-0.5f + t * (0.33333333f + t * (-0.25f + t * 0.2f))));
            float w = (u >= 0.984375f) ? -pp : (l2u * -0.69314718f);
            float l2w = __builtin_amdgcn_logf(w);           // log2(w)
            float d2 = fmaxf(__builtin_fmaf(-2.0f, acc[nt][r], x2), 1e-12f);
            float dist = __builtin_amdgcn_sqrtf(d2);
            float lg2 = __builtin_fmaf(-0.72134752f, dist, -0.5f * l2w);
            float e = __builtin_amdgcn_exp2f(lg2);
            u4[nt][r] = e;
            ss += e;
        }
    }
    ss += __shfl_xor(ss, 16);
    ss += __shfl_xor(ss, 32);   // row sum for row lcol (this V-chunk)

    // cross-wave Z-sum via xbuf (free: all waves past the afr barrier)
    if (lane < 16) xbuf[wave * 16 + lane] = ss;
    asm volatile("s_waitcnt lgkmcnt(0)" ::: "memory");
    __builtin_amdgcn_s_barrier();

    float Z = 0.f;
#pragma unroll
    for (int w = 0; w < WVA; ++w) Z += xbuf[w * 16 + lcol];
    const float rinv = 1.0f / Z;

    // ---- normalize in regs; prob -> LDS bf16 in sigma-slot order ----
    // pe[nt][r] (v = vb+16nt+4lrow+r) -> slot (wave*4+(nt>>1))*32 + lrow*8
    //   + (nt&1)*4 + r  (== kernel-B read layout), XOR-swizzled by row.
    unsigned short* pb = reinterpret_cast<unsigned short*>(gbuf);
#pragma unroll
    for (int nt = 0; nt < 8; ++nt) {
        u4[nt][0] *= rinv; u4[nt][1] *= rinv;
        u4[nt][2] *= rinv; u4[nt][3] *= rinv;
        uint2 pk;
        __bf16 b0 = (__bf16)u4[nt][0], b1 = (__bf16)u4[nt][1];
        __bf16 b2 = (__bf16)u4[nt][2], b3 = (__bf16)u4[nt][3];
        pk.x = (unsigned int)__builtin_bit_cast(unsigned short, b0) |
               ((unsigned int)__builtin_bit_cast(unsigned short, b1) << 16);
        pk.y = (unsigned int)__builtin_bit_cast(unsigned short, b2) |
               ((unsigned int)__builtin_bit_cast(unsigned short, b3) << 16);
        const int s = (wave * 4 + (nt >> 1)) * 32 + lrow * 8 + (nt & 1) * 4;
        *reinterpret_cast<uint2*>(&pb[lcol * VV + (s ^ ((lcol & 7) << 3))]) = pk;
    }
    __syncthreads();   // prob tile visible (gbuf reads all done pre-sred)

    // ---- GEMM2: out_q[16][wave*32..+31] = prob[16][1024] @ cb ----
    f32x4 q[2];
    q[0] = (f32x4){0.f, 0.f, 0.f, 0.f};
    q[1] = (f32x4){0.f, 0.f, 0.f, 0.f};
    const unsigned short* bb0 = cbB + (size_t)(wave * 2) * 16384 + laneoff;
    const unsigned short* bb1 = bb0 + 16384;

#pragma unroll 4
    for (int kt = 0; kt < 32; ++kt) {
        bf16x8 pfr = __builtin_bit_cast(bf16x8,
            *reinterpret_cast<const uint32x4*>(
                &pb[lcol * VV + ((kt * 32 + lrow * 8) ^ ((lcol & 7) << 3))]));
        bf16x8 f0 = __builtin_bit_cast(bf16x8,
            *reinterpret_cast<const uint32x4*>(bb0 + kt * 512));
        bf16x8 f1 = __builtin_bit_cast(bf16x8,
            *reinterpret_cast<const uint32x4*>(bb1 + kt * 512));
        q[0] = __builtin_amdgcn_mfma_f32_16x16x32_bf16(pfr, f0, q[0], 0, 0, 0);
        q[1] = __builtin_amdgcn_mfma_f32_16x16x32_bf16(pfr, f1, q[1], 0, 0, 0);
    }

    // ---- out_p: per-lane float4 stores (exact f32, v-contiguous) ----
    {
        float* oprow = out_p + (size_t)(row0 + lcol) * VV + vb + lrow * 4;
#pragma unroll
        for (int nt = 0; nt < 8; ++nt)
            *reinterpret_cast<float4*>(oprow + nt * 16) =
                (float4){u4[nt][0], u4[nt][1], u4[nt][2], u4[nt][3]};
    }

    // ---- out_q: C[row = row0+lrow*4+r][d = wave*32 + nt2*16 + lcol] ----
    {
        float* qrow0 = out_q + (size_t)(row0 + lrow * 4) * DD + wave * 32 + lcol;
#pragma unroll
        for (int r = 0; r < 4; ++r) {
            float* qr = qrow0 + r * DD;
            qr[0]  = q[0][r];
            qr[16] = q[1][r];
        }
    }
}

extern "C" void kernel_launch(void* const* d_in, const int* in_sizes, int n_in,
                              void* d_out, int out_size, void* d_ws, size_t ws_size,
                              hipStream_t stream) {
    (void)in_sizes; (void)n_in; (void)out_size; (void)ws_size;
    const float* x   = (const float*)d_in[0];   // [16,4096,256]
    const float* cb  = (const float*)d_in[1];   // [1024,256]
    const float* gum = (const float*)d_in[2];   // [65536,1024]

    const int N = 16 * 4096;
    float* out_q = (float*)d_out;                       // [N][256]
    float* out_p = out_q + (size_t)N * DD;              // [N][1024]

    unsigned short* cbA = (unsigned short*)d_ws;        // 576 KB fragment-major
    unsigned short* cbB = cbA + (size_t)64 * KC1 * 128; // 512 KB fragment-major
    vq_prep_kernel<<<VV, 256, 0, stream>>>(cb, cbA, cbB);
    vq_main_kernel<<<N / BN, 512, 0, stream>>>(x, gum, cbA, cbB, out_q, out_p);
}